// Round 2
// baseline (979.906 us; speedup 1.0000x reference)
//
#include <hip/hip_runtime.h>

typedef _Float16 f16x2 __attribute__((ext_vector_type(2)));
typedef unsigned int ui4 __attribute__((ext_vector_type(4)));

__device__ __forceinline__ float sigmoidf(float x) { return 1.0f / (1.0f + __expf(-x)); }
__device__ __forceinline__ float tanh_f(float x)   { return 2.0f / (1.0f + __expf(-2.0f * x)) - 1.0f; }

__device__ __forceinline__ unsigned int pk2(float a, float b) {
    union { _Float16 h[2]; unsigned int u; } t;
    t.h[0] = (_Float16)a; t.h[1] = (_Float16)b;
    return t.u;
}
__device__ __forceinline__ unsigned short f16bits(float f) {
    union { _Float16 h; unsigned short u; } t; t.h = (_Float16)f; return t.u;
}
__device__ __forceinline__ float dot2f(unsigned int wa, unsigned int hb, float c) {
#if __has_builtin(__builtin_amdgcn_fdot2)
    return __builtin_amdgcn_fdot2(__builtin_bit_cast(f16x2, wa),
                                  __builtin_bit_cast(f16x2, hb), c, false);
#else
    f16x2 a = __builtin_bit_cast(f16x2, wa), b = __builtin_bit_cast(f16x2, hb);
    return c + (float)a.x * (float)b.x + (float)a.y * (float)b.y;
#endif
}

// ---------------------------------------------------------------------------
// K1: Conv1d (KS=7, pad 3) + ReLU.  x:(16,128,128) f32 -> h_cat[...,0:128] and xconvT
// grid (wc=16, b=16), block 128 (thread = out-channel)
// ---------------------------------------------------------------------------
__global__ void conv_kernel(const float* __restrict__ x,
                            const float* __restrict__ cw,
                            const float* __restrict__ cb,
                            float* __restrict__ h_cat,
                            float* __restrict__ xconvT)
{
    const int wc = blockIdx.x, b = blockIdx.y, tid = threadIdx.x;
    __shared__ float xs[14][128];
    const int w0 = wc * 8;
#pragma unroll
    for (int i = 0; i < 14; ++i) {
        int row = w0 - 3 + i;
        xs[i][tid] = (row >= 0 && row < 128) ? x[(b * 128 + row) * 128 + tid] : 0.f;
    }
    __syncthreads();
    float bias = cb[tid];
    float acc[8];
#pragma unroll
    for (int j = 0; j < 8; ++j) acc[j] = bias;
    const float* wrow = cw + tid * 896; // conv_w[co][ci][t], 128*7 per co
    for (int ci = 0; ci < 128; ++ci) {
        float wv[7];
#pragma unroll
        for (int t = 0; t < 7; ++t) wv[t] = wrow[ci * 7 + t];
#pragma unroll
        for (int t = 0; t < 7; ++t) {
#pragma unroll
            for (int j = 0; j < 8; ++j) acc[j] += xs[j + t][ci] * wv[t];
        }
    }
#pragma unroll
    for (int j = 0; j < 8; ++j) {
        float v = fmaxf(acc[j], 0.f);
        h_cat [(b * 128 + w0 + j) * 384 + tid] = v;  // xconv slice of h_cat
        xconvT[(b * 128 + tid) * 128 + w0 + j] = v;  // transposed copy
    }
}

// ---------------------------------------------------------------------------
// K2: GATv2 lin projection, factored: P = v@Wl^T + b, Q = v@Wr^T
// (leaky-relu is applied AFTER the sum, so cat@W.T factors exactly)
// grid 2048 (row = b*128+node), block 256 (thread = embed dim e)
// ---------------------------------------------------------------------------
__global__ void lin_kernel(const float* __restrict__ v, int vstride,
                           const float* __restrict__ lw,
                           const float* __restrict__ lb,
                           float* __restrict__ P, float* __restrict__ Q)
{
    const int row = blockIdx.x, tid = threadIdx.x;
    __shared__ float vs[128];
    if (tid < 128) vs[tid] = v[(long)row * vstride + tid];
    __syncthreads();
    const float* wr = lw + tid * 256;
    float accP = lb[tid], accQ = 0.f;
    for (int d = 0; d < 128; ++d) {
        accP += vs[d] * wr[d];
        accQ += vs[d] * wr[128 + d];
    }
    P[(long)row * 256 + tid] = accP;
    Q[(long)row * 256 + tid] = accQ;
}

// ---------------------------------------------------------------------------
// K3: GAT attention: e[j]=lrelu(P_i+Q_j)·a + bias[i][j], softmax_j, out=sigmoid(attn@v)
// grid 2048 (b,i), block 256.
// mode 0 (feature): out[b,i,d] -> h_cat[b][d][128+i];  mode 1 (temporal): -> h_cat[b][i][256+d]
// ---------------------------------------------------------------------------
__global__ void gat_kernel(const float* __restrict__ P, const float* __restrict__ Q,
                           const float* __restrict__ a,
                           const float* __restrict__ bias,
                           const float* __restrict__ vbase, int vstride,
                           float* __restrict__ h_cat, int mode)
{
    const int bid = blockIdx.x;
    const int b = bid >> 7, i = bid & 127;
    const int tid = threadIdx.x;
    __shared__ float Ps[256], as_[256], ej[128], red[8], op[256];
    __shared__ float Qs[32 * 260];

    Ps[tid]  = P[(long)(b * 128 + i) * 256 + tid];
    as_[tid] = a[tid];

    const int jl = tid >> 3, c = tid & 7;
    for (int j0 = 0; j0 < 128; j0 += 32) {
        __syncthreads();
        for (int c2 = 0; c2 < 32; ++c2) {
            int flat = c2 * 256 + tid;
            int jj = flat >> 8, e = flat & 255;
            Qs[jj * 260 + e] = Q[(long)(b * 128 + j0 + jj) * 256 + e];
        }
        __syncthreads();
        float p = 0.f;
        for (int k = 0; k < 32; ++k) {
            int e = c + 8 * k;
            float hv = Ps[e] + Qs[jl * 260 + e];
            hv = (hv > 0.f) ? hv : 0.2f * hv;
            p += hv * as_[e];
        }
        p += __shfl_xor(p, 1);
        p += __shfl_xor(p, 2);
        p += __shfl_xor(p, 4);
        if (c == 0) ej[j0 + jl] = p + bias[i * 128 + j0 + jl];
    }
    __syncthreads();
    // softmax over 128
    {
        float v = (tid < 128) ? ej[tid] : -1e30f;
#pragma unroll
        for (int off = 32; off >= 1; off >>= 1) v = fmaxf(v, __shfl_xor(v, off));
        if ((tid & 63) == 0) red[tid >> 6] = v;
        __syncthreads();
        float m = fmaxf(fmaxf(red[0], red[1]), fmaxf(red[2], red[3]));
        float p = (tid < 128) ? __expf(ej[tid] - m) : 0.f;
        float s = p;
#pragma unroll
        for (int off = 32; off >= 1; off >>= 1) s += __shfl_xor(s, off);
        if ((tid & 63) == 0) red[4 + (tid >> 6)] = s;
        __syncthreads();
        float stot = red[4] + red[5] + red[6] + red[7];
        if (tid < 128) ej[tid] = p / stot;
        __syncthreads();
    }
    // out = sigmoid(attn @ v)
    const int half = tid >> 7, d = tid & 127;
    float part = 0.f;
    for (int j = half * 64; j < half * 64 + 64; ++j)
        part += ej[j] * vbase[(long)(b * 128 + j) * vstride + d];
    op[tid] = part;
    __syncthreads();
    if (tid < 128) {
        float o = sigmoidf(op[tid] + op[tid + 128]);
        if (mode == 0)
            h_cat[(long)b * 49152 + tid * 384 + 128 + i] = o;
        else
            h_cat[(long)b * 49152 + i * 384 + 256 + tid] = o;
    }
}

// ---------------------------------------------------------------------------
// K4: encoder input projection gi = h_cat @ w_ih^T + b_ih   (2048,384)@(384,768)
// grid (tc=16, b=16), block 256
// ---------------------------------------------------------------------------
__global__ void gi_kernel(const float* __restrict__ h_cat,
                          const float* __restrict__ w_ih,
                          const float* __restrict__ b_ih,
                          float* __restrict__ gi)
{
    const int tc = blockIdx.x, b = blockIdx.y, tid = threadIdx.x;
    __shared__ float hs[8][384];
    for (int row = 0; row < 8; ++row)
        for (int part = 0; part < 2; ++part) {
            int idx = part * 256 + tid;
            if (idx < 384) hs[row][idx] = h_cat[(long)(b * 128 + tc * 8 + row) * 384 + idx];
        }
    __syncthreads();
    float acc[3][8];
#pragma unroll
    for (int g = 0; g < 3; ++g) {
        float bias = b_ih[g * 256 + tid];
#pragma unroll
        for (int row = 0; row < 8; ++row) acc[g][row] = bias;
    }
    for (int d = 0; d < 384; ++d) {
        float w0 = w_ih[(0 * 256 + tid) * 384 + d];
        float w1 = w_ih[(1 * 256 + tid) * 384 + d];
        float w2 = w_ih[(2 * 256 + tid) * 384 + d];
#pragma unroll
        for (int row = 0; row < 8; ++row) {
            float hv = hs[row][d];
            acc[0][row] += hv * w0;
            acc[1][row] += hv * w1;
            acc[2][row] += hv * w2;
        }
    }
    for (int row = 0; row < 8; ++row)
#pragma unroll
        for (int g = 0; g < 3; ++g)
            gi[(long)(b * 128 + tc * 8 + row) * 768 + g * 256 + tid] = acc[g][row];
}

// ---------------------------------------------------------------------------
// K5: both GRUs, batch-split across 16 blocks (1 block = 1 batch = 1 CU).
// 512 threads: thread t -> hidden j = t>>1, k-half = t&1. Each thread holds the
// three gate rows w_hh[{j,256+j,512+j}][half*128 .. +128) as packed fp16 pairs
// in 192 VGPRs; h state stays fp32 in the thread register; h is broadcast per
// step via LDS as packed fp16; v_dot2_f32_f16 does the matvec; pair-reduce via
// shfl_xor(1). One barrier per step (parity double-buffered hpk).
// Decoder input: repeat_interleave identity -> gi_t = he[2t]*C0 + he[2t+1]*C1 + b_ih
// where C0/C1 are column-half sums of dec_w_ih (computed once, half-split+shfl).
// ---------------------------------------------------------------------------
__global__ void __launch_bounds__(512)
gru16_kernel(const float* __restrict__ gi,
             const float* __restrict__ w_hh,
             const float* __restrict__ b_hh,
             const float* __restrict__ dec_w_ih,
             const float* __restrict__ dec_w_hh,
             const float* __restrict__ dec_b_ih,
             const float* __restrict__ dec_b_hh,
             float* __restrict__ h_end,
             float* __restrict__ dec_out)
{
    const int b    = blockIdx.x;
    const int tid  = threadIdx.x;
    const int j    = tid >> 1;   // hidden index 0..255
    const int half = tid & 1;    // k-half

    __shared__ __align__(16) unsigned short hpk[2][256]; // packed f16 h, [parity][j]
    __shared__ float he[256];

    unsigned int wr[3][64];
    float bh[3];
#pragma unroll
    for (int g = 0; g < 3; ++g) {
        const float2* row = (const float2*)(w_hh + (long)(g * 256 + j) * 256 + half * 128);
        bh[g] = b_hh[g * 256 + j];
#pragma unroll
        for (int i = 0; i < 64; ++i) { float2 v = row[i]; wr[g][i] = pk2(v.x, v.y); }
    }
    if (tid < 256) { hpk[0][tid] = 0; hpk[1][tid] = 0; }
    float h = 0.f;
    __syncthreads();

    const float* gib = gi + (long)b * 128 * 768;
    float g0 = gib[j], g1 = gib[256 + j], g2 = gib[512 + j];

    // ======== encoder: 128 steps ========
    for (int t = 0; t < 128; ++t) {
        const int par = t & 1;
        float n0 = 0.f, n1 = 0.f, n2 = 0.f;
        if (t < 127) {
            const float* p = gib + (long)(t + 1) * 768;
            n0 = p[j]; n1 = p[256 + j]; n2 = p[512 + j];
        }
        float a0 = 0.f, a1 = 0.f, a2 = 0.f;
        const ui4* hp = (const ui4*)(((const unsigned int*)hpk[par]) + half * 64);
#pragma unroll
        for (int i = 0; i < 16; ++i) {
            ui4 hv = hp[i];
#pragma unroll
            for (int e = 0; e < 4; ++e) {
                a0 = dot2f(wr[0][i * 4 + e], hv[e], a0);
                a1 = dot2f(wr[1][i * 4 + e], hv[e], a1);
                a2 = dot2f(wr[2][i * 4 + e], hv[e], a2);
            }
        }
        a0 += __shfl_xor(a0, 1);
        a1 += __shfl_xor(a1, 1);
        a2 += __shfl_xor(a2, 1);
        float rr = sigmoidf(g0 + a0 + bh[0]);
        float zz = sigmoidf(g1 + a1 + bh[1]);
        float nn = tanh_f  (g2 + rr * (a2 + bh[2]));
        h = (1.f - zz) * nn + zz * h;
        if (!half) hpk[par ^ 1][j] = f16bits(h);
        g0 = n0; g1 = n1; g2 = n2;
        __syncthreads();
    }

    // ---- h_end, switch to decoder ----
    if (!half) { he[j] = h; h_end[b * 256 + j] = h; }
    if (tid < 256) { hpk[0][tid] = 0; hpk[1][tid] = 0; }

#pragma unroll
    for (int g = 0; g < 3; ++g) {
        const float2* row = (const float2*)(dec_w_hh + (long)(g * 256 + j) * 256 + half * 128);
        bh[g] = dec_b_hh[g * 256 + j];
#pragma unroll
        for (int i = 0; i < 64; ++i) { float2 v = row[i]; wr[g][i] = pk2(v.x, v.y); }
    }
    // C0/C1 column-half sums of dec_w_ih: my half's sum, then exchange with pair
    float c0[3], c1[3], bi[3];
#pragma unroll
    for (int g = 0; g < 3; ++g) {
        const float* row = dec_w_ih + (long)(g * 256 + j) * 256 + half * 128;
        float s = 0.f;
        for (int d = 0; d < 128; ++d) s += row[d];
        float other = __shfl_xor(s, 1);
        c0[g] = half ? other : s;
        c1[g] = half ? s : other;
        bi[g] = dec_b_ih[g * 256 + j];
    }
    h = 0.f;
    __syncthreads();

    // ======== decoder: 128 steps ========
    for (int t = 0; t < 128; ++t) {
        const int par = t & 1;
        float e0 = he[2 * t], e1 = he[2 * t + 1];
        float a0 = 0.f, a1 = 0.f, a2 = 0.f;
        const ui4* hp = (const ui4*)(((const unsigned int*)hpk[par]) + half * 64);
#pragma unroll
        for (int i = 0; i < 16; ++i) {
            ui4 hv = hp[i];
#pragma unroll
            for (int e = 0; e < 4; ++e) {
                a0 = dot2f(wr[0][i * 4 + e], hv[e], a0);
                a1 = dot2f(wr[1][i * 4 + e], hv[e], a1);
                a2 = dot2f(wr[2][i * 4 + e], hv[e], a2);
            }
        }
        a0 += __shfl_xor(a0, 1);
        a1 += __shfl_xor(a1, 1);
        a2 += __shfl_xor(a2, 1);
        float rr = sigmoidf(e0 * c0[0] + e1 * c1[0] + bi[0] + a0 + bh[0]);
        float zz = sigmoidf(e0 * c0[1] + e1 * c1[1] + bi[1] + a1 + bh[1]);
        float nn = tanh_f  (e0 * c0[2] + e1 * c1[2] + bi[2] + rr * (a2 + bh[2]));
        h = (1.f - zz) * nn + zz * h;
        if (!half) {
            hpk[par ^ 1][j] = f16bits(h);
            dec_out[((long)b * 128 + t) * 256 + j] = h;
        }
        __syncthreads();
    }
}

// ---------------------------------------------------------------------------
// K6: forecast MLP: pred = relu(h_end@fc1^T+b)@fc2^T+b.  grid 16, block 256
// ---------------------------------------------------------------------------
__global__ void mlp_kernel(const float* __restrict__ h_end,
                           const float* __restrict__ fc1_w,
                           const float* __restrict__ fc1_b,
                           const float* __restrict__ fc2_w,
                           const float* __restrict__ fc2_b,
                           float* __restrict__ out)
{
    const int b = blockIdx.x, tid = threadIdx.x;
    __shared__ float hv[256], hid[256];
    hv[tid] = h_end[b * 256 + tid];
    __syncthreads();
    float acc = fc1_b[tid];
    const float* wr = fc1_w + tid * 256;
    for (int d = 0; d < 256; ++d) acc += hv[d] * wr[d];
    hid[tid] = fmaxf(acc, 0.f);
    __syncthreads();
    if (tid < 128) {
        float a2 = fc2_b[tid];
        const float* w2 = fc2_w + tid * 256;
        for (int d = 0; d < 256; ++d) a2 += hid[d] * w2[d];
        out[b * 128 + tid] = a2;
    }
}

// ---------------------------------------------------------------------------
// K7: recons = dec_out @ rec_fc_w^T + b.  grid 2048 (row=b*128+t), block 128
// ---------------------------------------------------------------------------
__global__ void recon_kernel(const float* __restrict__ dec_out,
                             const float* __restrict__ rec_w,
                             const float* __restrict__ rec_b,
                             float* __restrict__ out)
{
    const int row = blockIdx.x, tid = threadIdx.x;
    __shared__ float dv[256];
    dv[tid]       = dec_out[(long)row * 256 + tid];
    dv[tid + 128] = dec_out[(long)row * 256 + 128 + tid];
    __syncthreads();
    float acc = rec_b[tid];
    const float* wr = rec_w + tid * 256;
    for (int d = 0; d < 256; ++d) acc += dv[d] * wr[d];
    out[(long)row * 128 + tid] = acc;
}

// ---------------------------------------------------------------------------
extern "C" void kernel_launch(void* const* d_in, const int* in_sizes, int n_in,
                              void* d_out, int out_size, void* d_ws, size_t ws_size,
                              hipStream_t stream)
{
    const float* x        = (const float*)d_in[0];
    const float* conv_w   = (const float*)d_in[1];
    const float* conv_b   = (const float*)d_in[2];
    const float* fg_lin_w = (const float*)d_in[3];
    const float* fg_lin_b = (const float*)d_in[4];
    const float* fg_a     = (const float*)d_in[5];
    const float* fg_bias  = (const float*)d_in[6];
    const float* tg_lin_w = (const float*)d_in[7];
    const float* tg_lin_b = (const float*)d_in[8];
    const float* tg_a     = (const float*)d_in[9];
    const float* tg_bias  = (const float*)d_in[10];
    const float* gru_w_ih = (const float*)d_in[11];
    const float* gru_w_hh = (const float*)d_in[12];
    const float* gru_b_ih = (const float*)d_in[13];
    const float* gru_b_hh = (const float*)d_in[14];
    const float* fc1_w    = (const float*)d_in[15];
    const float* fc1_b    = (const float*)d_in[16];
    const float* fc2_w    = (const float*)d_in[17];
    const float* fc2_b    = (const float*)d_in[18];
    const float* dec_w_ih = (const float*)d_in[19];
    const float* dec_w_hh = (const float*)d_in[20];
    const float* dec_b_ih = (const float*)d_in[21];
    const float* dec_b_hh = (const float*)d_in[22];
    const float* rec_fc_w = (const float*)d_in[23];
    const float* rec_fc_b = (const float*)d_in[24];
    float* out = (float*)d_out;

    float* ws      = (float*)d_ws;
    float* h_cat   = ws;                  // 16*128*384 = 786432
    float* xconvT  = h_cat + 786432;      // 262144
    float* Pf      = xconvT + 262144;     // 524288
    float* Qf      = Pf + 524288;         // 524288
    float* Pt      = Qf + 524288;         // 524288
    float* Qt      = Pt + 524288;         // 524288
    float* gi      = Qt + 524288;         // 16*128*768 = 1572864
    float* h_end   = gi + 1572864;        // 4096
    float* dec_out = h_end + 4096;        // 524288

    conv_kernel<<<dim3(16, 16), 128, 0, stream>>>(x, conv_w, conv_b, h_cat, xconvT);
    lin_kernel<<<2048, 256, 0, stream>>>(xconvT, 128, fg_lin_w, fg_lin_b, Pf, Qf);
    lin_kernel<<<2048, 256, 0, stream>>>(h_cat, 384, tg_lin_w, tg_lin_b, Pt, Qt);
    gat_kernel<<<2048, 256, 0, stream>>>(Pf, Qf, fg_a, fg_bias, xconvT, 128, h_cat, 0);
    gat_kernel<<<2048, 256, 0, stream>>>(Pt, Qt, tg_a, tg_bias, h_cat, 384, h_cat, 1);
    gi_kernel<<<dim3(16, 16), 256, 0, stream>>>(h_cat, gru_w_ih, gru_b_ih, gi);
    gru16_kernel<<<16, 512, 0, stream>>>(gi, gru_w_hh, gru_b_hh, dec_w_ih, dec_w_hh,
                                         dec_b_ih, dec_b_hh, h_end, dec_out);
    mlp_kernel<<<16, 256, 0, stream>>>(h_end, fc1_w, fc1_b, fc2_w, fc2_b, out);
    recon_kernel<<<2048, 128, 0, stream>>>(dec_out, rec_fc_w, rec_fc_b, out + 2048);
}

// Round 3
// 844.307 us; speedup vs baseline: 1.1606x; 1.1606x over previous
//
#include <hip/hip_runtime.h>

typedef _Float16 f16x2 __attribute__((ext_vector_type(2)));
typedef unsigned int ui4 __attribute__((ext_vector_type(4)));

__device__ __forceinline__ float fast_rcp(float x) {
#if __has_builtin(__builtin_amdgcn_rcpf)
    return __builtin_amdgcn_rcpf(x);
#else
    return 1.0f / x;
#endif
}
__device__ __forceinline__ float sigmoidf(float x) { return fast_rcp(1.0f + __expf(-x)); }
__device__ __forceinline__ float tanh_f(float x)   { return 2.0f * fast_rcp(1.0f + __expf(-2.0f * x)) - 1.0f; }

__device__ __forceinline__ unsigned int pk2(float a, float b) {
    union { _Float16 h[2]; unsigned int u; } t;
    t.h[0] = (_Float16)a; t.h[1] = (_Float16)b;
    return t.u;
}
__device__ __forceinline__ unsigned short f16bits(float f) {
    union { _Float16 h; unsigned short u; } t; t.h = (_Float16)f; return t.u;
}
__device__ __forceinline__ float dot2f(unsigned int wa, unsigned int hb, float c) {
#if __has_builtin(__builtin_amdgcn_fdot2)
    return __builtin_amdgcn_fdot2(__builtin_bit_cast(f16x2, wa),
                                  __builtin_bit_cast(f16x2, hb), c, false);
#else
    f16x2 a = __builtin_bit_cast(f16x2, wa), b = __builtin_bit_cast(f16x2, hb);
    return c + (float)a.x * (float)b.x + (float)a.y * (float)b.y;
#endif
}

// ---------------------------------------------------------------------------
// K1: Conv1d (KS=7, pad 3) + ReLU.  x:(16,128,128) f32 -> h_cat[...,0:128] and xconvT
// grid (wc=16, b=16), block 128 (thread = out-channel)
// ---------------------------------------------------------------------------
__global__ void conv_kernel(const float* __restrict__ x,
                            const float* __restrict__ cw,
                            const float* __restrict__ cb,
                            float* __restrict__ h_cat,
                            float* __restrict__ xconvT)
{
    const int wc = blockIdx.x, b = blockIdx.y, tid = threadIdx.x;
    __shared__ float xs[14][128];
    const int w0 = wc * 8;
#pragma unroll
    for (int i = 0; i < 14; ++i) {
        int row = w0 - 3 + i;
        xs[i][tid] = (row >= 0 && row < 128) ? x[(b * 128 + row) * 128 + tid] : 0.f;
    }
    __syncthreads();
    float bias = cb[tid];
    float acc[8];
#pragma unroll
    for (int j = 0; j < 8; ++j) acc[j] = bias;
    const float* wrow = cw + tid * 896; // conv_w[co][ci][t], 128*7 per co
    for (int ci = 0; ci < 128; ++ci) {
        float wv[7];
#pragma unroll
        for (int t = 0; t < 7; ++t) wv[t] = wrow[ci * 7 + t];
#pragma unroll
        for (int t = 0; t < 7; ++t) {
#pragma unroll
            for (int j = 0; j < 8; ++j) acc[j] += xs[j + t][ci] * wv[t];
        }
    }
#pragma unroll
    for (int j = 0; j < 8; ++j) {
        float v = fmaxf(acc[j], 0.f);
        h_cat [(b * 128 + w0 + j) * 384 + tid] = v;
        xconvT[(b * 128 + tid) * 128 + w0 + j] = v;
    }
}

// ---------------------------------------------------------------------------
// K2: GATv2 lin projection, factored: P = v@Wl^T + b, Q = v@Wr^T
// grid 2048 (row = b*128+node), block 256 (thread = embed dim e). float4 weights.
// ---------------------------------------------------------------------------
__global__ void lin_kernel(const float* __restrict__ v, int vstride,
                           const float* __restrict__ lw,
                           const float* __restrict__ lb,
                           float* __restrict__ P, float* __restrict__ Q)
{
    const int row = blockIdx.x, tid = threadIdx.x;
    __shared__ __align__(16) float vs[128];
    if (tid < 128) vs[tid] = v[(long)row * vstride + tid];
    __syncthreads();
    const float4* wp = (const float4*)(lw + tid * 256);
    const float4* wq = wp + 32;
    float p0 = lb[tid], p1 = 0.f, q0 = 0.f, q1 = 0.f;
#pragma unroll 4
    for (int i = 0; i < 32; i += 2) {
        float4 a = wp[i], b = wp[i + 1], c = wq[i], d = wq[i + 1];
        float4 h0 = *(const float4*)&vs[i * 4], h1 = *(const float4*)&vs[i * 4 + 4];
        p0 += a.x * h0.x + a.y * h0.y + a.z * h0.z + a.w * h0.w;
        p1 += b.x * h1.x + b.y * h1.y + b.z * h1.z + b.w * h1.w;
        q0 += c.x * h0.x + c.y * h0.y + c.z * h0.z + c.w * h0.w;
        q1 += d.x * h1.x + d.y * h1.y + d.z * h1.z + d.w * h1.w;
    }
    P[(long)row * 256 + tid] = p0 + p1;
    Q[(long)row * 256 + tid] = q0 + q1;
}

// ---------------------------------------------------------------------------
// K3: GAT attention: e[j]=lrelu(P_i+Q_j)·a + bias[i][j], softmax_j, out=sigmoid(attn@v)
// grid 2048 (b,i), block 256.
// mode 0 (feature): -> h_cat[b][d][128+i];  mode 1 (temporal): -> h_cat[b][i][256+d]
// ---------------------------------------------------------------------------
__global__ void gat_kernel(const float* __restrict__ P, const float* __restrict__ Q,
                           const float* __restrict__ a,
                           const float* __restrict__ bias,
                           const float* __restrict__ vbase, int vstride,
                           float* __restrict__ h_cat, int mode)
{
    const int bid = blockIdx.x;
    const int b = bid >> 7, i = bid & 127;
    const int tid = threadIdx.x;
    __shared__ __align__(16) float Ps[256], as_[256], ej[128], red[8], op[256];
    __shared__ __align__(16) float Qs[32 * 264];

    Ps[tid]  = P[(long)(b * 128 + i) * 256 + tid];
    as_[tid] = a[tid];

    const int jl = tid >> 3, c = tid & 7;
    for (int j0 = 0; j0 < 128; j0 += 32) {
        __syncthreads();
#pragma unroll
        for (int r = 0; r < 8; ++r) {          // 2048 float4 = 32 rows x 64
            int flat = r * 256 + tid;
            int jj = flat >> 6, e4 = flat & 63;
            *(float4*)&Qs[jj * 264 + e4 * 4] =
                *(const float4*)&Q[(long)(b * 128 + j0 + jj) * 256 + e4 * 4];
        }
        __syncthreads();
        float p = 0.f;
        for (int k = 0; k < 32; ++k) {
            int e = c + 8 * k;
            float hv = Ps[e] + Qs[jl * 264 + e];
            hv = (hv > 0.f) ? hv : 0.2f * hv;
            p += hv * as_[e];
        }
        p += __shfl_xor(p, 1);
        p += __shfl_xor(p, 2);
        p += __shfl_xor(p, 4);
        if (c == 0) ej[j0 + jl] = p + bias[i * 128 + j0 + jl];
    }
    __syncthreads();
    // softmax over 128
    {
        float v = (tid < 128) ? ej[tid] : -1e30f;
#pragma unroll
        for (int off = 32; off >= 1; off >>= 1) v = fmaxf(v, __shfl_xor(v, off));
        if ((tid & 63) == 0) red[tid >> 6] = v;
        __syncthreads();
        float m = fmaxf(fmaxf(red[0], red[1]), fmaxf(red[2], red[3]));
        float p = (tid < 128) ? __expf(ej[tid] - m) : 0.f;
        float s = p;
#pragma unroll
        for (int off = 32; off >= 1; off >>= 1) s += __shfl_xor(s, off);
        if ((tid & 63) == 0) red[4 + (tid >> 6)] = s;
        __syncthreads();
        float rs = fast_rcp(red[4] + red[5] + red[6] + red[7]);
        if (tid < 128) ej[tid] = p * rs;
        __syncthreads();
    }
    // out = sigmoid(attn @ v), 4 partials to pipeline the strided loads
    const int half = tid >> 7, d = tid & 127;
    const float* vb = vbase + ((long)(b * 128 + half * 64)) * vstride + d;
    float p0 = 0.f, p1 = 0.f, p2 = 0.f, p3 = 0.f;
    for (int j = 0; j < 64; j += 4) {
        p0 += ej[half * 64 + j]     * vb[(long)(j)     * vstride];
        p1 += ej[half * 64 + j + 1] * vb[(long)(j + 1) * vstride];
        p2 += ej[half * 64 + j + 2] * vb[(long)(j + 2) * vstride];
        p3 += ej[half * 64 + j + 3] * vb[(long)(j + 3) * vstride];
    }
    op[tid] = (p0 + p1) + (p2 + p3);
    __syncthreads();
    if (tid < 128) {
        float o = sigmoidf(op[tid] + op[tid + 128]);
        if (mode == 0)
            h_cat[(long)b * 49152 + tid * 384 + 128 + i] = o;
        else
            h_cat[(long)b * 49152 + i * 384 + 256 + tid] = o;
    }
}

// ---------------------------------------------------------------------------
// K4: encoder input projection gi = h_cat @ w_ih^T + b_ih   (2048,384)@(384,768)
// grid (tc=16, b=16), block 256. float4 weights + LDS float4 broadcasts.
// ---------------------------------------------------------------------------
__global__ void gi_kernel(const float* __restrict__ h_cat,
                          const float* __restrict__ w_ih,
                          const float* __restrict__ b_ih,
                          float* __restrict__ gi)
{
    const int tc = blockIdx.x, b = blockIdx.y, tid = threadIdx.x;
    __shared__ __align__(16) float hs[8][384];
    for (int row = 0; row < 8; ++row)
        for (int part = 0; part < 2; ++part) {
            int idx = part * 256 + tid;
            if (idx < 384) hs[row][idx] = h_cat[(long)(b * 128 + tc * 8 + row) * 384 + idx];
        }
    __syncthreads();
    float acc[3][8];
#pragma unroll
    for (int g = 0; g < 3; ++g) {
        float bias = b_ih[g * 256 + tid];
#pragma unroll
        for (int row = 0; row < 8; ++row) acc[g][row] = bias;
    }
    const float4* wp0 = (const float4*)(w_ih + (long)(0 * 256 + tid) * 384);
    const float4* wp1 = (const float4*)(w_ih + (long)(1 * 256 + tid) * 384);
    const float4* wp2 = (const float4*)(w_ih + (long)(2 * 256 + tid) * 384);
    for (int d4 = 0; d4 < 96; ++d4) {
        float4 w0 = wp0[d4], w1 = wp1[d4], w2 = wp2[d4];
#pragma unroll
        for (int row = 0; row < 8; ++row) {
            float4 h = *(const float4*)&hs[row][d4 * 4];
            acc[0][row] += h.x * w0.x + h.y * w0.y + h.z * w0.z + h.w * w0.w;
            acc[1][row] += h.x * w1.x + h.y * w1.y + h.z * w1.z + h.w * w1.w;
            acc[2][row] += h.x * w2.x + h.y * w2.y + h.z * w2.z + h.w * w2.w;
        }
    }
    for (int row = 0; row < 8; ++row)
#pragma unroll
        for (int g = 0; g < 3; ++g)
            gi[(long)(b * 128 + tc * 8 + row) * 768 + g * 256 + tid] = acc[g][row];
}

// ---------------------------------------------------------------------------
// K5: both GRUs, batch-split across 16 blocks (1 block = 1 batch = 1 CU).
// 512 threads: thread t -> hidden j = t>>1, k-half = t&1. w_hh rows as packed
// fp16 pairs in 192 REAL VGPRs -- __launch_bounds__(512,2) gives the 256-VGPR
// budget (R2's plain (512) capped at 128 and AGPR-spilled wr: 410us).
// 4 accumulators per gate (chain depth 64 -> 16). One barrier/step.
// ---------------------------------------------------------------------------
__global__ void __launch_bounds__(512, 2)
gru16_kernel(const float* __restrict__ gi,
             const float* __restrict__ w_hh,
             const float* __restrict__ b_hh,
             const float* __restrict__ dec_w_ih,
             const float* __restrict__ dec_w_hh,
             const float* __restrict__ dec_b_ih,
             const float* __restrict__ dec_b_hh,
             float* __restrict__ h_end,
             float* __restrict__ dec_out)
{
    const int b    = blockIdx.x;
    const int tid  = threadIdx.x;
    const int j    = tid >> 1;   // hidden index 0..255
    const int half = tid & 1;    // k-half

    __shared__ __align__(16) unsigned short hpk[2][256]; // packed f16 h, [parity][j]
    __shared__ float he[256];

    unsigned int wr[3][64];
    float bh[3];
#pragma unroll
    for (int g = 0; g < 3; ++g) {
        const float2* row = (const float2*)(w_hh + (long)(g * 256 + j) * 256 + half * 128);
        bh[g] = b_hh[g * 256 + j];
#pragma unroll
        for (int i = 0; i < 64; ++i) { float2 v = row[i]; wr[g][i] = pk2(v.x, v.y); }
    }
    if (tid < 256) { hpk[0][tid] = 0; hpk[1][tid] = 0; }
    float h = 0.f;
    __syncthreads();

    const float* gib = gi + (long)b * 128 * 768;
    float g0 = gib[j], g1 = gib[256 + j], g2 = gib[512 + j];

    // ======== encoder: 128 steps ========
    for (int t = 0; t < 128; ++t) {
        const int par = t & 1;
        float n0 = 0.f, n1 = 0.f, n2 = 0.f;
        if (t < 127) {
            const float* p = gib + (long)(t + 1) * 768;
            n0 = p[j]; n1 = p[256 + j]; n2 = p[512 + j];
        }
        float aa0[4] = {}, aa1[4] = {}, aa2[4] = {};
        const ui4* hp = (const ui4*)(((const unsigned int*)hpk[par]) + half * 64);
#pragma unroll
        for (int i = 0; i < 16; ++i) {
            ui4 hv = hp[i];
#pragma unroll
            for (int e = 0; e < 4; ++e) {
                aa0[e] = dot2f(wr[0][i * 4 + e], hv[e], aa0[e]);
                aa1[e] = dot2f(wr[1][i * 4 + e], hv[e], aa1[e]);
                aa2[e] = dot2f(wr[2][i * 4 + e], hv[e], aa2[e]);
            }
        }
        float a0 = (aa0[0] + aa0[1]) + (aa0[2] + aa0[3]);
        float a1 = (aa1[0] + aa1[1]) + (aa1[2] + aa1[3]);
        float a2 = (aa2[0] + aa2[1]) + (aa2[2] + aa2[3]);
        a0 += __shfl_xor(a0, 1);
        a1 += __shfl_xor(a1, 1);
        a2 += __shfl_xor(a2, 1);
        float rr = sigmoidf(g0 + a0 + bh[0]);
        float zz = sigmoidf(g1 + a1 + bh[1]);
        float nn = tanh_f  (g2 + rr * (a2 + bh[2]));
        h = (1.f - zz) * nn + zz * h;
        if (!half) hpk[par ^ 1][j] = f16bits(h);
        g0 = n0; g1 = n1; g2 = n2;
        __syncthreads();
    }

    // ---- h_end, switch to decoder ----
    if (!half) { he[j] = h; h_end[b * 256 + j] = h; }
    if (tid < 256) { hpk[0][tid] = 0; hpk[1][tid] = 0; }

#pragma unroll
    for (int g = 0; g < 3; ++g) {
        const float2* row = (const float2*)(dec_w_hh + (long)(g * 256 + j) * 256 + half * 128);
        bh[g] = dec_b_hh[g * 256 + j];
#pragma unroll
        for (int i = 0; i < 64; ++i) { float2 v = row[i]; wr[g][i] = pk2(v.x, v.y); }
    }
    // C0/C1 column-half sums of dec_w_ih
    float c0[3], c1[3], bi[3];
#pragma unroll
    for (int g = 0; g < 3; ++g) {
        const float* row = dec_w_ih + (long)(g * 256 + j) * 256 + half * 128;
        float s = 0.f;
        for (int d = 0; d < 128; ++d) s += row[d];
        float other = __shfl_xor(s, 1);
        c0[g] = half ? other : s;
        c1[g] = half ? s : other;
        bi[g] = dec_b_ih[g * 256 + j];
    }
    h = 0.f;
    __syncthreads();

    // ======== decoder: 128 steps; gi_t = he[2t]*C0 + he[2t+1]*C1 + b_ih ========
    for (int t = 0; t < 128; ++t) {
        const int par = t & 1;
        float e0 = he[2 * t], e1 = he[2 * t + 1];
        float aa0[4] = {}, aa1[4] = {}, aa2[4] = {};
        const ui4* hp = (const ui4*)(((const unsigned int*)hpk[par]) + half * 64);
#pragma unroll
        for (int i = 0; i < 16; ++i) {
            ui4 hv = hp[i];
#pragma unroll
            for (int e = 0; e < 4; ++e) {
                aa0[e] = dot2f(wr[0][i * 4 + e], hv[e], aa0[e]);
                aa1[e] = dot2f(wr[1][i * 4 + e], hv[e], aa1[e]);
                aa2[e] = dot2f(wr[2][i * 4 + e], hv[e], aa2[e]);
            }
        }
        float a0 = (aa0[0] + aa0[1]) + (aa0[2] + aa0[3]);
        float a1 = (aa1[0] + aa1[1]) + (aa1[2] + aa1[3]);
        float a2 = (aa2[0] + aa2[1]) + (aa2[2] + aa2[3]);
        a0 += __shfl_xor(a0, 1);
        a1 += __shfl_xor(a1, 1);
        a2 += __shfl_xor(a2, 1);
        float rr = sigmoidf(e0 * c0[0] + e1 * c1[0] + bi[0] + a0 + bh[0]);
        float zz = sigmoidf(e0 * c0[1] + e1 * c1[1] + bi[1] + a1 + bh[1]);
        float nn = tanh_f  (e0 * c0[2] + e1 * c1[2] + bi[2] + rr * (a2 + bh[2]));
        h = (1.f - zz) * nn + zz * h;
        if (!half) {
            hpk[par ^ 1][j] = f16bits(h);
            dec_out[((long)b * 128 + t) * 256 + j] = h;
        }
        __syncthreads();
    }
}

// ---------------------------------------------------------------------------
// K6: forecast MLP: pred = relu(h_end@fc1^T+b)@fc2^T+b.  grid 16, block 256
// ---------------------------------------------------------------------------
__global__ void mlp_kernel(const float* __restrict__ h_end,
                           const float* __restrict__ fc1_w,
                           const float* __restrict__ fc1_b,
                           const float* __restrict__ fc2_w,
                           const float* __restrict__ fc2_b,
                           float* __restrict__ out)
{
    const int b = blockIdx.x, tid = threadIdx.x;
    __shared__ __align__(16) float hv[256], hid[256];
    hv[tid] = h_end[b * 256 + tid];
    __syncthreads();
    float acc = fc1_b[tid], acc2 = 0.f;
    const float4* wr = (const float4*)(fc1_w + tid * 256);
#pragma unroll 4
    for (int i = 0; i < 64; i += 2) {
        float4 w0 = wr[i], w1 = wr[i + 1];
        float4 h0 = *(const float4*)&hv[i * 4], h1 = *(const float4*)&hv[i * 4 + 4];
        acc  += w0.x * h0.x + w0.y * h0.y + w0.z * h0.z + w0.w * h0.w;
        acc2 += w1.x * h1.x + w1.y * h1.y + w1.z * h1.z + w1.w * h1.w;
    }
    hid[tid] = fmaxf(acc + acc2, 0.f);
    __syncthreads();
    if (tid < 128) {
        float a2 = fc2_b[tid], a3 = 0.f;
        const float4* w2 = (const float4*)(fc2_w + tid * 256);
#pragma unroll 4
        for (int i = 0; i < 64; i += 2) {
            float4 w0 = w2[i], w1 = w2[i + 1];
            float4 h0 = *(const float4*)&hid[i * 4], h1 = *(const float4*)&hid[i * 4 + 4];
            a2 += w0.x * h0.x + w0.y * h0.y + w0.z * h0.z + w0.w * h0.w;
            a3 += w1.x * h1.x + w1.y * h1.y + w1.z * h1.z + w1.w * h1.w;
        }
        out[b * 128 + tid] = a2 + a3;
    }
}

// ---------------------------------------------------------------------------
// K7: recons = dec_out @ rec_fc_w^T + b.  grid 2048 (row=b*128+t), block 128
// ---------------------------------------------------------------------------
__global__ void recon_kernel(const float* __restrict__ dec_out,
                             const float* __restrict__ rec_w,
                             const float* __restrict__ rec_b,
                             float* __restrict__ out)
{
    const int row = blockIdx.x, tid = threadIdx.x;
    __shared__ __align__(16) float dv[256];
    dv[tid]       = dec_out[(long)row * 256 + tid];
    dv[tid + 128] = dec_out[(long)row * 256 + 128 + tid];
    __syncthreads();
    float acc = rec_b[tid], acc2 = 0.f;
    const float4* wr = (const float4*)(rec_w + tid * 256);
#pragma unroll 4
    for (int i = 0; i < 64; i += 2) {
        float4 w0 = wr[i], w1 = wr[i + 1];
        float4 h0 = *(const float4*)&dv[i * 4], h1 = *(const float4*)&dv[i * 4 + 4];
        acc  += w0.x * h0.x + w0.y * h0.y + w0.z * h0.z + w0.w * h0.w;
        acc2 += w1.x * h1.x + w1.y * h1.y + w1.z * h1.z + w1.w * h1.w;
    }
    out[(long)row * 128 + tid] = acc + acc2;
}

// ---------------------------------------------------------------------------
extern "C" void kernel_launch(void* const* d_in, const int* in_sizes, int n_in,
                              void* d_out, int out_size, void* d_ws, size_t ws_size,
                              hipStream_t stream)
{
    const float* x        = (const float*)d_in[0];
    const float* conv_w   = (const float*)d_in[1];
    const float* conv_b   = (const float*)d_in[2];
    const float* fg_lin_w = (const float*)d_in[3];
    const float* fg_lin_b = (const float*)d_in[4];
    const float* fg_a     = (const float*)d_in[5];
    const float* fg_bias  = (const float*)d_in[6];
    const float* tg_lin_w = (const float*)d_in[7];
    const float* tg_lin_b = (const float*)d_in[8];
    const float* tg_a     = (const float*)d_in[9];
    const float* tg_bias  = (const float*)d_in[10];
    const float* gru_w_ih = (const float*)d_in[11];
    const float* gru_w_hh = (const float*)d_in[12];
    const float* gru_b_ih = (const float*)d_in[13];
    const float* gru_b_hh = (const float*)d_in[14];
    const float* fc1_w    = (const float*)d_in[15];
    const float* fc1_b    = (const float*)d_in[16];
    const float* fc2_w    = (const float*)d_in[17];
    const float* fc2_b    = (const float*)d_in[18];
    const float* dec_w_ih = (const float*)d_in[19];
    const float* dec_w_hh = (const float*)d_in[20];
    const float* dec_b_ih = (const float*)d_in[21];
    const float* dec_b_hh = (const float*)d_in[22];
    const float* rec_fc_w = (const float*)d_in[23];
    const float* rec_fc_b = (const float*)d_in[24];
    float* out = (float*)d_out;

    float* ws      = (float*)d_ws;
    float* h_cat   = ws;                  // 16*128*384 = 786432
    float* xconvT  = h_cat + 786432;      // 262144
    float* Pf      = xconvT + 262144;     // 524288
    float* Qf      = Pf + 524288;         // 524288
    float* Pt      = Qf + 524288;         // 524288
    float* Qt      = Pt + 524288;         // 524288
    float* gi      = Qt + 524288;         // 16*128*768 = 1572864
    float* h_end   = gi + 1572864;        // 4096
    float* dec_out = h_end + 4096;        // 524288

    conv_kernel<<<dim3(16, 16), 128, 0, stream>>>(x, conv_w, conv_b, h_cat, xconvT);
    lin_kernel<<<2048, 256, 0, stream>>>(xconvT, 128, fg_lin_w, fg_lin_b, Pf, Qf);
    lin_kernel<<<2048, 256, 0, stream>>>(h_cat, 384, tg_lin_w, tg_lin_b, Pt, Qt);
    gat_kernel<<<2048, 256, 0, stream>>>(Pf, Qf, fg_a, fg_bias, xconvT, 128, h_cat, 0);
    gat_kernel<<<2048, 256, 0, stream>>>(Pt, Qt, tg_a, tg_bias, h_cat, 384, h_cat, 1);
    gi_kernel<<<dim3(16, 16), 256, 0, stream>>>(h_cat, gru_w_ih, gru_b_ih, gi);
    gru16_kernel<<<16, 512, 0, stream>>>(gi, gru_w_hh, gru_b_hh, dec_w_ih, dec_w_hh,
                                         dec_b_ih, dec_b_hh, h_end, dec_out);
    mlp_kernel<<<16, 256, 0, stream>>>(h_end, fc1_w, fc1_b, fc2_w, fc2_b, out);
    recon_kernel<<<2048, 128, 0, stream>>>(dec_out, rec_fc_w, rec_fc_b, out + 2048);
}

// Round 4
// 843.561 us; speedup vs baseline: 1.1616x; 1.0009x over previous
//
#include <hip/hip_runtime.h>

typedef _Float16 f16x2 __attribute__((ext_vector_type(2)));
typedef unsigned int ui4 __attribute__((ext_vector_type(4)));

__device__ __forceinline__ float fast_rcp(float x) {
#if __has_builtin(__builtin_amdgcn_rcpf)
    return __builtin_amdgcn_rcpf(x);
#else
    return 1.0f / x;
#endif
}
__device__ __forceinline__ float sigmoidf(float x) { return fast_rcp(1.0f + __expf(-x)); }
__device__ __forceinline__ float tanh_f(float x)   { return 2.0f * fast_rcp(1.0f + __expf(-2.0f * x)) - 1.0f; }

__device__ __forceinline__ unsigned int pk2(float a, float b) {
    union { _Float16 h[2]; unsigned int u; } t;
    t.h[0] = (_Float16)a; t.h[1] = (_Float16)b;
    return t.u;
}
__device__ __forceinline__ unsigned short f16bits(float f) {
    union { _Float16 h; unsigned short u; } t; t.h = (_Float16)f; return t.u;
}
__device__ __forceinline__ float dot2f(unsigned int wa, unsigned int hb, float c) {
#if __has_builtin(__builtin_amdgcn_fdot2)
    return __builtin_amdgcn_fdot2(__builtin_bit_cast(f16x2, wa),
                                  __builtin_bit_cast(f16x2, hb), c, false);
#else
    f16x2 a = __builtin_bit_cast(f16x2, wa), b = __builtin_bit_cast(f16x2, hb);
    return c + (float)a.x * (float)b.x + (float)a.y * (float)b.y;
#endif
}

// ---------------------------------------------------------------------------
// K1: Conv1d (KS=7, pad 3) + ReLU.  x:(16,128,128) f32 -> h_cat[...,0:128] and xconvT
// grid (wc=16, b=16), block 128 (thread = out-channel)
// ---------------------------------------------------------------------------
__global__ void conv_kernel(const float* __restrict__ x,
                            const float* __restrict__ cw,
                            const float* __restrict__ cb,
                            float* __restrict__ h_cat,
                            float* __restrict__ xconvT)
{
    const int wc = blockIdx.x, b = blockIdx.y, tid = threadIdx.x;
    __shared__ float xs[14][128];
    const int w0 = wc * 8;
#pragma unroll
    for (int i = 0; i < 14; ++i) {
        int row = w0 - 3 + i;
        xs[i][tid] = (row >= 0 && row < 128) ? x[(b * 128 + row) * 128 + tid] : 0.f;
    }
    __syncthreads();
    float bias = cb[tid];
    float acc[8];
#pragma unroll
    for (int j = 0; j < 8; ++j) acc[j] = bias;
    const float* wrow = cw + tid * 896;
    for (int ci = 0; ci < 128; ++ci) {
        float wv[7];
#pragma unroll
        for (int t = 0; t < 7; ++t) wv[t] = wrow[ci * 7 + t];
#pragma unroll
        for (int t = 0; t < 7; ++t) {
#pragma unroll
            for (int j = 0; j < 8; ++j) acc[j] += xs[j + t][ci] * wv[t];
        }
    }
#pragma unroll
    for (int j = 0; j < 8; ++j) {
        float v = fmaxf(acc[j], 0.f);
        h_cat [(b * 128 + w0 + j) * 384 + tid] = v;
        xconvT[(b * 128 + tid) * 128 + w0 + j] = v;
    }
}

// ---------------------------------------------------------------------------
// K2: GATv2 lin projection, factored: P = v@Wl^T + b, Q = v@Wr^T
// ---------------------------------------------------------------------------
__global__ void lin_kernel(const float* __restrict__ v, int vstride,
                           const float* __restrict__ lw,
                           const float* __restrict__ lb,
                           float* __restrict__ P, float* __restrict__ Q)
{
    const int row = blockIdx.x, tid = threadIdx.x;
    __shared__ __align__(16) float vs[128];
    if (tid < 128) vs[tid] = v[(long)row * vstride + tid];
    __syncthreads();
    const float4* wp = (const float4*)(lw + tid * 256);
    const float4* wq = wp + 32;
    float p0 = lb[tid], p1 = 0.f, q0 = 0.f, q1 = 0.f;
#pragma unroll 4
    for (int i = 0; i < 32; i += 2) {
        float4 a = wp[i], b = wp[i + 1], c = wq[i], d = wq[i + 1];
        float4 h0 = *(const float4*)&vs[i * 4], h1 = *(const float4*)&vs[i * 4 + 4];
        p0 += a.x * h0.x + a.y * h0.y + a.z * h0.z + a.w * h0.w;
        p1 += b.x * h1.x + b.y * h1.y + b.z * h1.z + b.w * h1.w;
        q0 += c.x * h0.x + c.y * h0.y + c.z * h0.z + c.w * h0.w;
        q1 += d.x * h1.x + d.y * h1.y + d.z * h1.z + d.w * h1.w;
    }
    P[(long)row * 256 + tid] = p0 + p1;
    Q[(long)row * 256 + tid] = q0 + q1;
}

// ---------------------------------------------------------------------------
// K3: GAT attention
// ---------------------------------------------------------------------------
__global__ void gat_kernel(const float* __restrict__ P, const float* __restrict__ Q,
                           const float* __restrict__ a,
                           const float* __restrict__ bias,
                           const float* __restrict__ vbase, int vstride,
                           float* __restrict__ h_cat, int mode)
{
    const int bid = blockIdx.x;
    const int b = bid >> 7, i = bid & 127;
    const int tid = threadIdx.x;
    __shared__ __align__(16) float Ps[256], as_[256], ej[128], red[8], op[256];
    __shared__ __align__(16) float Qs[32 * 264];

    Ps[tid]  = P[(long)(b * 128 + i) * 256 + tid];
    as_[tid] = a[tid];

    const int jl = tid >> 3, c = tid & 7;
    for (int j0 = 0; j0 < 128; j0 += 32) {
        __syncthreads();
#pragma unroll
        for (int r = 0; r < 8; ++r) {
            int flat = r * 256 + tid;
            int jj = flat >> 6, e4 = flat & 63;
            *(float4*)&Qs[jj * 264 + e4 * 4] =
                *(const float4*)&Q[(long)(b * 128 + j0 + jj) * 256 + e4 * 4];
        }
        __syncthreads();
        float p = 0.f;
        for (int k = 0; k < 32; ++k) {
            int e = c + 8 * k;
            float hv = Ps[e] + Qs[jl * 264 + e];
            hv = (hv > 0.f) ? hv : 0.2f * hv;
            p += hv * as_[e];
        }
        p += __shfl_xor(p, 1);
        p += __shfl_xor(p, 2);
        p += __shfl_xor(p, 4);
        if (c == 0) ej[j0 + jl] = p + bias[i * 128 + j0 + jl];
    }
    __syncthreads();
    {
        float v = (tid < 128) ? ej[tid] : -1e30f;
#pragma unroll
        for (int off = 32; off >= 1; off >>= 1) v = fmaxf(v, __shfl_xor(v, off));
        if ((tid & 63) == 0) red[tid >> 6] = v;
        __syncthreads();
        float m = fmaxf(fmaxf(red[0], red[1]), fmaxf(red[2], red[3]));
        float p = (tid < 128) ? __expf(ej[tid] - m) : 0.f;
        float s = p;
#pragma unroll
        for (int off = 32; off >= 1; off >>= 1) s += __shfl_xor(s, off);
        if ((tid & 63) == 0) red[4 + (tid >> 6)] = s;
        __syncthreads();
        float rs = fast_rcp(red[4] + red[5] + red[6] + red[7]);
        if (tid < 128) ej[tid] = p * rs;
        __syncthreads();
    }
    // out = sigmoid(attn @ v); unroll 8 -> more outstanding L2 loads
    const int half = tid >> 7, d = tid & 127;
    const float* vb = vbase + ((long)(b * 128 + half * 64)) * vstride + d;
    float p0 = 0.f, p1 = 0.f, p2 = 0.f, p3 = 0.f;
#pragma unroll 8
    for (int j = 0; j < 64; j += 4) {
        p0 += ej[half * 64 + j]     * vb[(long)(j)     * vstride];
        p1 += ej[half * 64 + j + 1] * vb[(long)(j + 1) * vstride];
        p2 += ej[half * 64 + j + 2] * vb[(long)(j + 2) * vstride];
        p3 += ej[half * 64 + j + 3] * vb[(long)(j + 3) * vstride];
    }
    op[tid] = (p0 + p1) + (p2 + p3);
    __syncthreads();
    if (tid < 128) {
        float o = sigmoidf(op[tid] + op[tid + 128]);
        if (mode == 0)
            h_cat[(long)b * 49152 + tid * 384 + 128 + i] = o;
        else
            h_cat[(long)b * 49152 + i * 384 + 256 + tid] = o;
    }
}

// ---------------------------------------------------------------------------
// K4: encoder input projection gi = h_cat @ w_ih^T + b_ih
// ---------------------------------------------------------------------------
__global__ void gi_kernel(const float* __restrict__ h_cat,
                          const float* __restrict__ w_ih,
                          const float* __restrict__ b_ih,
                          float* __restrict__ gi)
{
    const int tc = blockIdx.x, b = blockIdx.y, tid = threadIdx.x;
    __shared__ __align__(16) float hs[8][384];
    for (int row = 0; row < 8; ++row)
        for (int part = 0; part < 2; ++part) {
            int idx = part * 256 + tid;
            if (idx < 384) hs[row][idx] = h_cat[(long)(b * 128 + tc * 8 + row) * 384 + idx];
        }
    __syncthreads();
    float acc[3][8];
#pragma unroll
    for (int g = 0; g < 3; ++g) {
        float bias = b_ih[g * 256 + tid];
#pragma unroll
        for (int row = 0; row < 8; ++row) acc[g][row] = bias;
    }
    const float4* wp0 = (const float4*)(w_ih + (long)(0 * 256 + tid) * 384);
    const float4* wp1 = (const float4*)(w_ih + (long)(1 * 256 + tid) * 384);
    const float4* wp2 = (const float4*)(w_ih + (long)(2 * 256 + tid) * 384);
    for (int d4 = 0; d4 < 96; ++d4) {
        float4 w0 = wp0[d4], w1 = wp1[d4], w2 = wp2[d4];
#pragma unroll
        for (int row = 0; row < 8; ++row) {
            float4 h = *(const float4*)&hs[row][d4 * 4];
            acc[0][row] += h.x * w0.x + h.y * w0.y + h.z * w0.z + h.w * w0.w;
            acc[1][row] += h.x * w1.x + h.y * w1.y + h.z * w1.z + h.w * w1.w;
            acc[2][row] += h.x * w2.x + h.y * w2.y + h.z * w2.z + h.w * w2.w;
        }
    }
    for (int row = 0; row < 8; ++row)
#pragma unroll
        for (int g = 0; g < 3; ++g)
            gi[(long)(b * 128 + tc * 8 + row) * 768 + g * 256 + tid] = acc[g][row];
}

// ---------------------------------------------------------------------------
// K5: both GRUs, batch-split (1 block = 1 batch = 1 CU), 512 threads.
// Steady-state step touches ONLY LDS: gi is staged into LDS in 32-step chunks
// (one vmcnt drain per chunk instead of a global-load drain at EVERY step's
// barrier -- the R3 stall: __syncthreads emits s_waitcnt vmcnt(0) and the
// per-step gi prefetch/dec_out stores put ~1-2.7k cyc of HBM latency into the
// recurrence each step). dec_out is buffered in the same LDS and flushed per
// chunk. w_hh rows live as packed fp16 in 192 regs (AGPR-backed is fine:
// CDNA4 VALU reads AGPRs directly).
// ---------------------------------------------------------------------------
__global__ void __launch_bounds__(512, 2)
gru16_kernel(const float* __restrict__ gi,
             const float* __restrict__ w_hh,
             const float* __restrict__ b_hh,
             const float* __restrict__ dec_w_ih,
             const float* __restrict__ dec_w_hh,
             const float* __restrict__ dec_b_ih,
             const float* __restrict__ dec_b_hh,
             float* __restrict__ h_end,
             float* __restrict__ dec_out)
{
    const int b    = blockIdx.x;
    const int tid  = threadIdx.x;
    const int j    = tid >> 1;   // hidden index 0..255
    const int half = tid & 1;    // k-half

    __shared__ __align__(16) unsigned short hpk[2][256]; // packed f16 h
    __shared__ float he[256];
    __shared__ __align__(16) float gich[32 * 768];       // 96KB; decoder reuses as dec buffer

    unsigned int wr[3][64];
    float bh[3];
#pragma unroll
    for (int g = 0; g < 3; ++g) {
        const float4* row = (const float4*)(w_hh + (long)(g * 256 + j) * 256 + half * 128);
        bh[g] = b_hh[g * 256 + j];
#pragma unroll
        for (int i = 0; i < 32; ++i) {
            float4 v = row[i];
            wr[g][2 * i]     = pk2(v.x, v.y);
            wr[g][2 * i + 1] = pk2(v.z, v.w);
        }
    }
    if (tid < 256) { hpk[0][tid] = 0; hpk[1][tid] = 0; }
    float h = 0.f;

    const float* gib = gi + (long)b * 128 * 768;
    const unsigned int* hbase0 = ((const unsigned int*)hpk[0]) + half * 64;
    const unsigned int* hbase1 = ((const unsigned int*)hpk[1]) + half * 64;

    // ======== encoder: 4 chunks x 32 steps ========
    for (int cchunk = 0; cchunk < 4; ++cchunk) {
        // stage gi chunk (32 x 768 floats) into LDS; single vmcnt drain at barrier
        const float* gsrc = gib + (long)cchunk * 32 * 768;
#pragma unroll
        for (int i = 0; i < 12; ++i) {
            int idx = (i * 512 + tid) * 4;
            *(float4*)&gich[idx] = *(const float4*)&gsrc[idx];
        }
        __syncthreads();
        for (int tt = 0; tt < 32; ++tt) {
            const int t = cchunk * 32 + tt;
            const int par = t & 1;
            float g0 = gich[tt * 768 + j];
            float g1 = gich[tt * 768 + 256 + j];
            float g2 = gich[tt * 768 + 512 + j];
            float aa0[4] = {}, aa1[4] = {}, aa2[4] = {};
            const ui4* hp = (const ui4*)(par ? hbase1 : hbase0);
#pragma unroll
            for (int i = 0; i < 16; ++i) {
                ui4 hv = hp[i];
#pragma unroll
                for (int e = 0; e < 4; ++e) {
                    aa0[e] = dot2f(wr[0][i * 4 + e], hv[e], aa0[e]);
                    aa1[e] = dot2f(wr[1][i * 4 + e], hv[e], aa1[e]);
                    aa2[e] = dot2f(wr[2][i * 4 + e], hv[e], aa2[e]);
                }
            }
            float a0 = (aa0[0] + aa0[1]) + (aa0[2] + aa0[3]);
            float a1 = (aa1[0] + aa1[1]) + (aa1[2] + aa1[3]);
            float a2 = (aa2[0] + aa2[1]) + (aa2[2] + aa2[3]);
            a0 += __shfl_xor(a0, 1);
            a1 += __shfl_xor(a1, 1);
            a2 += __shfl_xor(a2, 1);
            float rr = sigmoidf(g0 + a0 + bh[0]);
            float zz = sigmoidf(g1 + a1 + bh[1]);
            float nn = tanh_f  (g2 + rr * (a2 + bh[2]));
            h = (1.f - zz) * nn + zz * h;
            if (!half) hpk[par ^ 1][j] = f16bits(h);
            __syncthreads();
        }
    }

    // ---- h_end, switch to decoder ----
    if (!half) { he[j] = h; h_end[b * 256 + j] = h; }
    if (tid < 256) { hpk[0][tid] = 0; hpk[1][tid] = 0; }

#pragma unroll
    for (int g = 0; g < 3; ++g) {
        const float4* row = (const float4*)(dec_w_hh + (long)(g * 256 + j) * 256 + half * 128);
        bh[g] = dec_b_hh[g * 256 + j];
#pragma unroll
        for (int i = 0; i < 32; ++i) {
            float4 v = row[i];
            wr[g][2 * i]     = pk2(v.x, v.y);
            wr[g][2 * i + 1] = pk2(v.z, v.w);
        }
    }
    // C0/C1 column-half sums of dec_w_ih
    float c0[3], c1[3], bi[3];
#pragma unroll
    for (int g = 0; g < 3; ++g) {
        const float4* row = (const float4*)(dec_w_ih + (long)(g * 256 + j) * 256 + half * 128);
        float s = 0.f;
#pragma unroll
        for (int i = 0; i < 32; ++i) { float4 v = row[i]; s += (v.x + v.y) + (v.z + v.w); }
        float other = __shfl_xor(s, 1);
        c0[g] = half ? other : s;
        c1[g] = half ? s : other;
        bi[g] = dec_b_ih[g * 256 + j];
    }
    h = 0.f;
    float* decbuf = gich; // reuse staging LDS as [32][256] output buffer
    __syncthreads();

    // ======== decoder: 4 chunks x 32 steps; gi_t = he[2t]*C0 + he[2t+1]*C1 + b_ih ========
    for (int cchunk = 0; cchunk < 4; ++cchunk) {
        for (int tt = 0; tt < 32; ++tt) {
            const int t = cchunk * 32 + tt;
            const int par = t & 1;
            float e0 = he[2 * t], e1 = he[2 * t + 1];
            float aa0[4] = {}, aa1[4] = {}, aa2[4] = {};
            const ui4* hp = (const ui4*)(par ? hbase1 : hbase0);
#pragma unroll
            for (int i = 0; i < 16; ++i) {
                ui4 hv = hp[i];
#pragma unroll
                for (int e = 0; e < 4; ++e) {
                    aa0[e] = dot2f(wr[0][i * 4 + e], hv[e], aa0[e]);
                    aa1[e] = dot2f(wr[1][i * 4 + e], hv[e], aa1[e]);
                    aa2[e] = dot2f(wr[2][i * 4 + e], hv[e], aa2[e]);
                }
            }
            float a0 = (aa0[0] + aa0[1]) + (aa0[2] + aa0[3]);
            float a1 = (aa1[0] + aa1[1]) + (aa1[2] + aa1[3]);
            float a2 = (aa2[0] + aa2[1]) + (aa2[2] + aa2[3]);
            a0 += __shfl_xor(a0, 1);
            a1 += __shfl_xor(a1, 1);
            a2 += __shfl_xor(a2, 1);
            float rr = sigmoidf(e0 * c0[0] + e1 * c1[0] + bi[0] + a0 + bh[0]);
            float zz = sigmoidf(e0 * c0[1] + e1 * c1[1] + bi[1] + a1 + bh[1]);
            float nn = tanh_f  (e0 * c0[2] + e1 * c1[2] + bi[2] + rr * (a2 + bh[2]));
            h = (1.f - zz) * nn + zz * h;
            if (!half) {
                hpk[par ^ 1][j] = f16bits(h);
                decbuf[tt * 256 + j] = h;
            }
            __syncthreads();
        }
        // flush chunk to global (stores drain at a later barrier, ~free)
#pragma unroll
        for (int i = 0; i < 4; ++i) {
            int idx = (i * 512 + tid) * 4;
            *(float4*)&dec_out[(long)b * 32768 + cchunk * 8192 + idx] = *(const float4*)&decbuf[idx];
        }
        __syncthreads(); // all flush reads done before next chunk overwrites decbuf
    }
}

// ---------------------------------------------------------------------------
// K6: forecast MLP
// ---------------------------------------------------------------------------
__global__ void mlp_kernel(const float* __restrict__ h_end,
                           const float* __restrict__ fc1_w,
                           const float* __restrict__ fc1_b,
                           const float* __restrict__ fc2_w,
                           const float* __restrict__ fc2_b,
                           float* __restrict__ out)
{
    const int b = blockIdx.x, tid = threadIdx.x;
    __shared__ __align__(16) float hv[256], hid[256];
    hv[tid] = h_end[b * 256 + tid];
    __syncthreads();
    float acc = fc1_b[tid], acc2 = 0.f;
    const float4* wr = (const float4*)(fc1_w + tid * 256);
#pragma unroll 4
    for (int i = 0; i < 64; i += 2) {
        float4 w0 = wr[i], w1 = wr[i + 1];
        float4 h0 = *(const float4*)&hv[i * 4], h1 = *(const float4*)&hv[i * 4 + 4];
        acc  += w0.x * h0.x + w0.y * h0.y + w0.z * h0.z + w0.w * h0.w;
        acc2 += w1.x * h1.x + w1.y * h1.y + w1.z * h1.z + w1.w * h1.w;
    }
    hid[tid] = fmaxf(acc + acc2, 0.f);
    __syncthreads();
    if (tid < 128) {
        float a2 = fc2_b[tid], a3 = 0.f;
        const float4* w2 = (const float4*)(fc2_w + tid * 256);
#pragma unroll 4
        for (int i = 0; i < 64; i += 2) {
            float4 w0 = w2[i], w1 = w2[i + 1];
            float4 h0 = *(const float4*)&hid[i * 4], h1 = *(const float4*)&hid[i * 4 + 4];
            a2 += w0.x * h0.x + w0.y * h0.y + w0.z * h0.z + w0.w * h0.w;
            a3 += w1.x * h1.x + w1.y * h1.y + w1.z * h1.z + w1.w * h1.w;
        }
        out[b * 128 + tid] = a2 + a3;
    }
}

// ---------------------------------------------------------------------------
// K7: recons = dec_out @ rec_fc_w^T + b
// ---------------------------------------------------------------------------
__global__ void recon_kernel(const float* __restrict__ dec_out,
                             const float* __restrict__ rec_w,
                             const float* __restrict__ rec_b,
                             float* __restrict__ out)
{
    const int row = blockIdx.x, tid = threadIdx.x;
    __shared__ __align__(16) float dv[256];
    dv[tid]       = dec_out[(long)row * 256 + tid];
    dv[tid + 128] = dec_out[(long)row * 256 + 128 + tid];
    __syncthreads();
    float acc = rec_b[tid], acc2 = 0.f;
    const float4* wr = (const float4*)(rec_w + tid * 256);
#pragma unroll 4
    for (int i = 0; i < 64; i += 2) {
        float4 w0 = wr[i], w1 = wr[i + 1];
        float4 h0 = *(const float4*)&dv[i * 4], h1 = *(const float4*)&dv[i * 4 + 4];
        acc  += w0.x * h0.x + w0.y * h0.y + w0.z * h0.z + w0.w * h0.w;
        acc2 += w1.x * h1.x + w1.y * h1.y + w1.z * h1.z + w1.w * h1.w;
    }
    out[(long)row * 128 + tid] = acc + acc2;
}

// ---------------------------------------------------------------------------
extern "C" void kernel_launch(void* const* d_in, const int* in_sizes, int n_in,
                              void* d_out, int out_size, void* d_ws, size_t ws_size,
                              hipStream_t stream)
{
    const float* x        = (const float*)d_in[0];
    const float* conv_w   = (const float*)d_in[1];
    const float* conv_b   = (const float*)d_in[2];
    const float* fg_lin_w = (const float*)d_in[3];
    const float* fg_lin_b = (const float*)d_in[4];
    const float* fg_a     = (const float*)d_in[5];
    const float* fg_bias  = (const float*)d_in[6];
    const float* tg_lin_w = (const float*)d_in[7];
    const float* tg_lin_b = (const float*)d_in[8];
    const float* tg_a     = (const float*)d_in[9];
    const float* tg_bias  = (const float*)d_in[10];
    const float* gru_w_ih = (const float*)d_in[11];
    const float* gru_w_hh = (const float*)d_in[12];
    const float* gru_b_ih = (const float*)d_in[13];
    const float* gru_b_hh = (const float*)d_in[14];
    const float* fc1_w    = (const float*)d_in[15];
    const float* fc1_b    = (const float*)d_in[16];
    const float* fc2_w    = (const float*)d_in[17];
    const float* fc2_b    = (const float*)d_in[18];
    const float* dec_w_ih = (const float*)d_in[19];
    const float* dec_w_hh = (const float*)d_in[20];
    const float* dec_b_ih = (const float*)d_in[21];
    const float* dec_b_hh = (const float*)d_in[22];
    const float* rec_fc_w = (const float*)d_in[23];
    const float* rec_fc_b = (const float*)d_in[24];
    float* out = (float*)d_out;

    float* ws      = (float*)d_ws;
    float* h_cat   = ws;                  // 16*128*384 = 786432
    float* xconvT  = h_cat + 786432;      // 262144
    float* Pf      = xconvT + 262144;     // 524288
    float* Qf      = Pf + 524288;         // 524288
    float* Pt      = Qf + 524288;         // 524288
    float* Qt      = Pt + 524288;         // 524288
    float* gi      = Qt + 524288;         // 16*128*768 = 1572864
    float* h_end   = gi + 1572864;        // 4096
    float* dec_out = h_end + 4096;        // 524288

    conv_kernel<<<dim3(16, 16), 128, 0, stream>>>(x, conv_w, conv_b, h_cat, xconvT);
    lin_kernel<<<2048, 256, 0, stream>>>(xconvT, 128, fg_lin_w, fg_lin_b, Pf, Qf);
    lin_kernel<<<2048, 256, 0, stream>>>(h_cat, 384, tg_lin_w, tg_lin_b, Pt, Qt);
    gat_kernel<<<2048, 256, 0, stream>>>(Pf, Qf, fg_a, fg_bias, xconvT, 128, h_cat, 0);
    gat_kernel<<<2048, 256, 0, stream>>>(Pt, Qt, tg_a, tg_bias, h_cat, 384, h_cat, 1);
    gi_kernel<<<dim3(16, 16), 256, 0, stream>>>(h_cat, gru_w_ih, gru_b_ih, gi);
    gru16_kernel<<<16, 512, 0, stream>>>(gi, gru_w_hh, gru_b_hh, dec_w_ih, dec_w_hh,
                                         dec_b_ih, dec_b_hh, h_end, dec_out);
    mlp_kernel<<<16, 256, 0, stream>>>(h_end, fc1_w, fc1_b, fc2_w, fc2_b, out);
    recon_kernel<<<2048, 128, 0, stream>>>(dec_out, rec_fc_w, rec_fc_b, out + 2048);
}